// Round 6
// baseline (613.712 us; speedup 1.0000x reference)
//
#include <hip/hip_runtime.h>

typedef unsigned short u16;
typedef __attribute__((ext_vector_type(4))) float f32x4;
typedef __attribute__((ext_vector_type(8))) __bf16 bf16x8;
typedef __attribute__((ext_vector_type(4))) unsigned int u32x4;

#define S_LEN 2048
#define D_DIM 1024
#define N_HEADS 16
#define DK 64
#define B_SZ 4

__device__ __forceinline__ u16 f2bf(float f) {
  unsigned int u = __float_as_uint(f);
  unsigned int r = (u + 0x7FFFu + ((u >> 16) & 1u)) >> 16;
  return (u16)r;
}
__device__ __forceinline__ f32x4 mfma16(u32x4 a, u32x4 b, f32x4 c) {
  return __builtin_amdgcn_mfma_f32_16x16x32_bf16(
      __builtin_bit_cast(bf16x8, a), __builtin_bit_cast(bf16x8, b), c, 0, 0, 0);
}

// ---- weight transpose+convert: WT[n][k] (bf16) = W[k][n] (f32) -------------
__global__ __launch_bounds__(256) void transpose_wf(const float* __restrict__ W,
                                                    u16* __restrict__ WT) {
  __shared__ float tb[32][33];
  const int tx = threadIdx.x & 31;
  const int ty0 = (threadIdx.x >> 5) << 2;
  const int bn = blockIdx.x << 5;
  const int bk = blockIdx.y << 5;
#pragma unroll
  for (int i = 0; i < 4; ++i)
    tb[ty0 + i][tx] = W[(size_t)(bk + ty0 + i) * D_DIM + bn + tx];
  __syncthreads();
#pragma unroll
  for (int i = 0; i < 4; ++i)
    WT[(size_t)(bn + ty0 + i) * D_DIM + bk + tx] = f2bf(tb[tx][ty0 + i]);
}

// ---- GEMM: dst = X[8192x1024] @ W + bias ------------------------------------
// BPRE=1: B from pre-transposed bf16 WT[N][K] (vectorized staging).
// BPRE=0: B from f32 W[K][N], transposed inline (chunk-swizzled scatter).
// AF32: A dtype. epi: 0=f32 [M][N]; 1=bf16 [B][H][S][DK]; 2=bf16 [B][H][DK][S].
template <int AF32, int BPRE>
__global__ __launch_bounds__(256) void gemm_xw(const void* __restrict__ Av,
                                               const void* __restrict__ Bv,
                                               const float* __restrict__ bias,
                                               void* __restrict__ dstv,
                                               const int epi, const float osc) {
  __shared__ __align__(16) u16 As[128 * 40];
  __shared__ __align__(16) u16 Bs[128 * 40];
  const int tid = threadIdx.x;
  const int lane = tid & 63;
  const int wid = tid >> 6;
  const int wr = wid >> 1, wc = wid & 1;
  const int lr = lane & 15, lg = lane >> 4;
  const int m0 = blockIdx.x * 128;
  const int n0 = blockIdx.y * 128;

  const float* Xf = (const float*)Av;
  const u16* Xh = (const u16*)Av;
  const float* Wf = (const float*)Bv;
  const u16* WT = (const u16*)Bv;

  f32x4 acc[4][4];
#pragma unroll
  for (int i = 0; i < 4; ++i)
#pragma unroll
    for (int j = 0; j < 4; ++j) acc[i][j] = (f32x4){0.f, 0.f, 0.f, 0.f};

  const int srow = tid >> 2;
  const int sko = (tid & 3) << 3;

  for (int k0 = 0; k0 < D_DIM; k0 += 32) {
    __syncthreads();
#pragma unroll
    for (int i = 0; i < 2; ++i) {
      const int row = srow + i * 64;
      union { u32x4 v; u16 u[8]; } pk;
      if (AF32) {
        const float* src = &Xf[(size_t)(m0 + row) * D_DIM + k0 + sko];
        f32x4 a0 = *(const f32x4*)src;
        f32x4 a1 = *(const f32x4*)(src + 4);
#pragma unroll
        for (int j = 0; j < 4; ++j) { pk.u[j] = f2bf(a0[j]); pk.u[4 + j] = f2bf(a1[j]); }
      } else {
        pk.v = *(const u32x4*)&Xh[(size_t)(m0 + row) * D_DIM + k0 + sko];
      }
      *(u32x4*)&As[row * 40 + sko] = pk.v;
    }
    if (BPRE) {
#pragma unroll
      for (int i = 0; i < 2; ++i) {
        const int row = srow + i * 64;
        u32x4 bch = *(const u32x4*)&WT[(size_t)(n0 + row) * D_DIM + k0 + sko];
        *(u32x4*)&Bs[row * 40 + sko] = bch;
      }
    } else {
#pragma unroll
      for (int i = 0; i < 2; ++i) {
        const int s = tid + (i << 8);
        const int kr = s >> 4;
        const int mN = s & 15;
        const int nc = mN << 3;
        const float* src = &Wf[(size_t)(k0 + kr) * D_DIM + n0 + nc];
        f32x4 w0 = *(const f32x4*)src;
        f32x4 w1 = *(const f32x4*)(src + 4);
        const int cb = (((kr >> 3) ^ (mN & 3)) << 3) + (kr & 7);
#pragma unroll
        for (int j = 0; j < 4; ++j) {
          Bs[(nc + j) * 40 + cb] = f2bf(w0[j]);
          Bs[(nc + 4 + j) * 40 + cb] = f2bf(w1[j]);
        }
      }
    }
    __syncthreads();
    u32x4 af[4], bfr[4];
#pragma unroll
    for (int mi = 0; mi < 4; ++mi)
      af[mi] = *(const u32x4*)&As[(wr * 64 + mi * 16 + lr) * 40 + lg * 8];
#pragma unroll
    for (int ni = 0; ni < 4; ++ni) {
      const int row = wc * 64 + ni * 16 + lr;
      if (BPRE)
        bfr[ni] = *(const u32x4*)&Bs[row * 40 + lg * 8];
      else
        bfr[ni] = *(const u32x4*)&Bs[row * 40 + ((lg ^ ((row >> 3) & 3)) << 3)];
    }
#pragma unroll
    for (int mi = 0; mi < 4; ++mi)
#pragma unroll
      for (int ni = 0; ni < 4; ++ni)
        acc[mi][ni] = mfma16(af[mi], bfr[ni], acc[mi][ni]);
  }

#pragma unroll
  for (int ni = 0; ni < 4; ++ni) {
    const int n = n0 + wc * 64 + ni * 16 + lr;
    const float bv = bias[n];
#pragma unroll
    for (int mi = 0; mi < 4; ++mi) {
      const int mb = m0 + wr * 64 + mi * 16 + lg * 4;
      if (epi == 2) {  // V^T: [B][H][DK][S]
        const int bb = mb >> 11, ss = mb & (S_LEN - 1);
        const int hh = n >> 6, dd = n & (DK - 1);
        union { u16 u[4]; unsigned long long q; } pk;
#pragma unroll
        for (int r = 0; r < 4; ++r) pk.u[r] = f2bf((acc[mi][ni][r] + bv) * osc);
        *(unsigned long long*)&((u16*)dstv)[((size_t)((bb * N_HEADS + hh) * DK + dd)) * S_LEN + ss] = pk.q;
      } else {
#pragma unroll
        for (int r = 0; r < 4; ++r) {
          const int m = mb + r;
          const float o = (acc[mi][ni][r] + bv) * osc;
          if (epi == 1) {
            const int bb = m >> 11, ss = m & (S_LEN - 1);
            const int hh = n >> 6, dd = n & (DK - 1);
            ((u16*)dstv)[(((size_t)(bb * N_HEADS + hh) * S_LEN) + ss) * DK + dd] = f2bf(o);
          } else {
            ((float*)dstv)[(size_t)m * D_DIM + n] = o;
          }
        }
      }
    }
  }
}

// ---- causal flash attention: ZERO barriers, per-wave independent ------------
// grid (S/64, H, B) reversed; 4 waves, wave w owns q rows [q0+16w,+16).
// K and V fragments straight from global (L1/L2-resident per head).
// No-max softmax (exp2-domain, |s| << 127). P bounced through PER-WAVE LDS
// (wave-internal ordering, no __syncthreads), XOR-chunk swizzled (<=2-way).
__global__ __launch_bounds__(256) void attn_kernel(const u16* __restrict__ Qb,
                                                   const u16* __restrict__ Kb,
                                                   const u16* __restrict__ VTb,
                                                   u16* __restrict__ Xb) {
  __shared__ __align__(16) u16 Pl[4][16 * 80];  // per-wave [q_local][kpos], swizzled

  const int tid = threadIdx.x;
  const int lane = tid & 63;
  const int w = tid >> 6;
  const int lr = lane & 15;
  const int lg = lane >> 4;
  const int lrhi = lr >> 3, lrlo = lr & 7;

  const int q0 = (int)(gridDim.x - 1 - blockIdx.x) * 64;  // heavy blocks first
  const int h = blockIdx.y;
  const int b = blockIdx.z;

  const u16* Qh = Qb + ((size_t)(b * N_HEADS + h)) * S_LEN * DK;
  const u16* Kh = Kb + ((size_t)(b * N_HEADS + h)) * S_LEN * DK;
  const u16* VTh = VTb + ((size_t)(b * N_HEADS + h)) * DK * S_LEN;
  u16* Plw = Pl[w];

  const int qrow_base = q0 + w * 16 + lg * 4;
  const int nt = (q0 >> 6) + 1;

  u32x4 qf[2];
#pragma unroll
  for (int g = 0; g < 2; ++g)
    qf[g] = *(const u32x4*)&Qh[(size_t)(q0 + w * 16 + lr) * DK + g * 32 + lg * 8];

  f32x4 xacc[4];
#pragma unroll
  for (int i = 0; i < 4; ++i) xacc[i] = (f32x4){0.f, 0.f, 0.f, 0.f};
  float plsum[4] = {0.f, 0.f, 0.f, 0.f};

  for (int t = 0; t < nt; ++t) {
    const int kp0 = t << 6;
    // QK^T from global K fragments
    f32x4 sc[4];
#pragma unroll
    for (int tt = 0; tt < 4; ++tt) sc[tt] = (f32x4){0.f, 0.f, 0.f, 0.f};
    __builtin_amdgcn_s_setprio(1);
#pragma unroll
    for (int g = 0; g < 2; ++g)
#pragma unroll
      for (int tt = 0; tt < 4; ++tt) {
        u32x4 kf = *(const u32x4*)&Kh[(size_t)(kp0 + tt * 16 + lr) * DK + g * 32 + lg * 8];
        sc[tt] = mfma16(qf[g], kf, sc[tt]);
      }
    __builtin_amdgcn_s_setprio(0);
    // no-max softmax; write P to per-wave LDS (swizzled: chunk ^= row&7)
#pragma unroll
    for (int tt = 0; tt < 4; ++tt)
#pragma unroll
      for (int r = 0; r < 4; ++r) {
        const float e = exp2f(sc[tt][r]);
        const float p = (kp0 + tt * 16 + lr > qrow_base + r) ? 0.f : e;
        plsum[r] += p;
        const int row = lg * 4 + r;
        const int chunk = (tt * 2 + lrhi) ^ (((lg & 1) << 2) + r);
        Plw[row * 80 + chunk * 8 + lrlo] = f2bf(p);
      }
    // P fragments (transposed view) + V fragments from global + PV
    u32x4 pf[2];
#pragma unroll
    for (int g = 0; g < 2; ++g)
      pf[g] = *(const u32x4*)&Plw[lr * 80 + (((g * 4 + lg) ^ lrlo) << 3)];
    __builtin_amdgcn_s_setprio(1);
#pragma unroll
    for (int db = 0; db < 4; ++db)
#pragma unroll
      for (int g = 0; g < 2; ++g) {
        u32x4 vf = *(const u32x4*)&VTh[(size_t)(db * 16 + lr) * S_LEN + kp0 + g * 32 + lg * 8];
        xacc[db] = mfma16(pf[g], vf, xacc[db]);
      }
    __builtin_amdgcn_s_setprio(0);
  }

  // deferred row-sum reduction (once per kernel)
#pragma unroll
  for (int d = 1; d < 16; d <<= 1)
#pragma unroll
    for (int r = 0; r < 4; ++r) plsum[r] += __shfl_xor(plsum[r], d);

#pragma unroll
  for (int r = 0; r < 4; ++r) {
    const float inv = 1.0f / fmaxf(plsum[r], 1e-30f);
    const int srow = qrow_base + r;
    const size_t base = ((size_t)b * S_LEN + srow) * D_DIM + h * DK;
#pragma unroll
    for (int db = 0; db < 4; ++db)
      Xb[base + db * 16 + lr] = f2bf(xacc[db][r] * inv);
  }
}

// ---- launcher ---------------------------------------------------------------
// d_out holds Qb+Kb (bf16, 33.55MB total = exactly out_size*4 bytes).
// ws: VTb(16.78MB) + Xb(16.78MB) [+ 4x WT bf16 (8.39MB) if ws_size allows].
extern "C" void kernel_launch(void* const* d_in, const int* in_sizes, int n_in,
                              void* d_out, int out_size, void* d_ws, size_t ws_size,
                              hipStream_t stream) {
  const float* q = (const float*)d_in[0];
  const float* k = (const float*)d_in[1];
  const float* v = (const float*)d_in[2];
  const float* Wq = (const float*)d_in[4];  const float* bq = (const float*)d_in[5];
  const float* Wk = (const float*)d_in[6];  const float* bk = (const float*)d_in[7];
  const float* Wv = (const float*)d_in[8];  const float* bv = (const float*)d_in[9];
  const float* Wo = (const float*)d_in[10]; const float* bo = (const float*)d_in[11];

  u16* Qb = (u16*)d_out;
  u16* Kb = Qb + (8u << 20);
  u16* VTb = (u16*)d_ws;
  u16* Xb = VTb + (8u << 20);

  const float scl = 0.125f * 1.4426950408889634f;  // 1/sqrt(DK) * log2(e)
  const dim3 tb(256);
  const size_t need = ((size_t)(8u << 20)) * 2 * 2 + 4 * ((size_t)(1u << 20)) * 2;

  if (ws_size >= need) {
    u16* WqT = Xb + (8u << 20);
    u16* WkT = WqT + (1u << 20);
    u16* WvT = WkT + (1u << 20);
    u16* WoT = WvT + (1u << 20);
    transpose_wf<<<dim3(32, 32), tb, 0, stream>>>(Wq, WqT);
    transpose_wf<<<dim3(32, 32), tb, 0, stream>>>(Wk, WkT);
    transpose_wf<<<dim3(32, 32), tb, 0, stream>>>(Wv, WvT);
    transpose_wf<<<dim3(32, 32), tb, 0, stream>>>(Wo, WoT);
    gemm_xw<1, 1><<<dim3(64, 8), tb, 0, stream>>>(q, WqT, bq, Qb, 1, scl);
    gemm_xw<1, 1><<<dim3(64, 8), tb, 0, stream>>>(k, WkT, bk, Kb, 1, 1.0f);
    gemm_xw<1, 1><<<dim3(64, 8), tb, 0, stream>>>(v, WvT, bv, VTb, 2, 1.0f);
    attn_kernel<<<dim3(S_LEN / 64, N_HEADS, B_SZ), tb, 0, stream>>>(Qb, Kb, VTb, Xb);
    gemm_xw<0, 1><<<dim3(64, 8), tb, 0, stream>>>(Xb, WoT, bo, d_out, 0, 1.0f);
  } else {
    gemm_xw<1, 0><<<dim3(64, 8), tb, 0, stream>>>(q, Wq, bq, Qb, 1, scl);
    gemm_xw<1, 0><<<dim3(64, 8), tb, 0, stream>>>(k, Wk, bk, Kb, 1, 1.0f);
    gemm_xw<1, 0><<<dim3(64, 8), tb, 0, stream>>>(v, Wv, bv, VTb, 2, 1.0f);
    attn_kernel<<<dim3(S_LEN / 64, N_HEADS, B_SZ), tb, 0, stream>>>(Qb, Kb, VTb, Xb);
    gemm_xw<0, 0><<<dim3(64, 8), tb, 0, stream>>>(Xb, Wo, bo, d_out, 0, 1.0f);
  }
}

// Round 7
// 336.226 us; speedup vs baseline: 1.8253x; 1.8253x over previous
//
#include <hip/hip_runtime.h>

typedef unsigned short u16;
typedef __attribute__((ext_vector_type(4))) float f32x4;
typedef __attribute__((ext_vector_type(8))) __bf16 bf16x8;
typedef __attribute__((ext_vector_type(4))) unsigned int u32x4;

#define S_LEN 2048
#define D_DIM 1024
#define N_HEADS 16
#define DK 64
#define B_SZ 4

__device__ __forceinline__ u16 f2bf(float f) {
  unsigned int u = __float_as_uint(f);
  unsigned int r = (u + 0x7FFFu + ((u >> 16) & 1u)) >> 16;
  return (u16)r;
}
__device__ __forceinline__ f32x4 mfma16(u32x4 a, u32x4 b, f32x4 c) {
  return __builtin_amdgcn_mfma_f32_16x16x32_bf16(
      __builtin_bit_cast(bf16x8, a), __builtin_bit_cast(bf16x8, b), c, 0, 0, 0);
}

// ---- weight transpose+convert: WT[n][k] (bf16) = W[k][n] (f32) -------------
__global__ __launch_bounds__(256) void transpose_wf(const float* __restrict__ W,
                                                    u16* __restrict__ WT) {
  __shared__ float tb[32][33];
  const int tx = threadIdx.x & 31;
  const int ty0 = (threadIdx.x >> 5) << 2;
  const int bn = blockIdx.x << 5;
  const int bk = blockIdx.y << 5;
#pragma unroll
  for (int i = 0; i < 4; ++i)
    tb[ty0 + i][tx] = W[(size_t)(bk + ty0 + i) * D_DIM + bn + tx];
  __syncthreads();
#pragma unroll
  for (int i = 0; i < 4; ++i)
    WT[(size_t)(bn + ty0 + i) * D_DIM + bk + tx] = f2bf(tb[tx][ty0 + i]);
}

// ---- GEMM: dst = X[8192x1024] @ W + bias ------------------------------------
// BPRE=1: B from pre-transposed bf16 WT[N][K] (vectorized staging).
// BPRE=0: B from f32 W[K][N], transposed inline (chunk-swizzled scatter).
// AF32: A dtype. epi: 0=f32 [M][N]; 1=bf16 [B][H][S][DK]; 2=bf16 [B][H][DK][S].
template <int AF32, int BPRE>
__global__ __launch_bounds__(256) void gemm_xw(const void* __restrict__ Av,
                                               const void* __restrict__ Bv,
                                               const float* __restrict__ bias,
                                               void* __restrict__ dstv,
                                               const int epi, const float osc) {
  __shared__ __align__(16) u16 As[128 * 40];
  __shared__ __align__(16) u16 Bs[128 * 40];
  const int tid = threadIdx.x;
  const int lane = tid & 63;
  const int wid = tid >> 6;
  const int wr = wid >> 1, wc = wid & 1;
  const int lr = lane & 15, lg = lane >> 4;
  const int m0 = blockIdx.x * 128;
  const int n0 = blockIdx.y * 128;

  const float* Xf = (const float*)Av;
  const u16* Xh = (const u16*)Av;
  const float* Wf = (const float*)Bv;
  const u16* WT = (const u16*)Bv;

  f32x4 acc[4][4];
#pragma unroll
  for (int i = 0; i < 4; ++i)
#pragma unroll
    for (int j = 0; j < 4; ++j) acc[i][j] = (f32x4){0.f, 0.f, 0.f, 0.f};

  const int srow = tid >> 2;
  const int sko = (tid & 3) << 3;

  for (int k0 = 0; k0 < D_DIM; k0 += 32) {
    __syncthreads();
#pragma unroll
    for (int i = 0; i < 2; ++i) {
      const int row = srow + i * 64;
      union { u32x4 v; u16 u[8]; } pk;
      if (AF32) {
        const float* src = &Xf[(size_t)(m0 + row) * D_DIM + k0 + sko];
        f32x4 a0 = *(const f32x4*)src;
        f32x4 a1 = *(const f32x4*)(src + 4);
#pragma unroll
        for (int j = 0; j < 4; ++j) { pk.u[j] = f2bf(a0[j]); pk.u[4 + j] = f2bf(a1[j]); }
      } else {
        pk.v = *(const u32x4*)&Xh[(size_t)(m0 + row) * D_DIM + k0 + sko];
      }
      *(u32x4*)&As[row * 40 + sko] = pk.v;
    }
    if (BPRE) {
#pragma unroll
      for (int i = 0; i < 2; ++i) {
        const int row = srow + i * 64;
        u32x4 bch = *(const u32x4*)&WT[(size_t)(n0 + row) * D_DIM + k0 + sko];
        *(u32x4*)&Bs[row * 40 + sko] = bch;
      }
    } else {
#pragma unroll
      for (int i = 0; i < 2; ++i) {
        const int s = tid + (i << 8);
        const int kr = s >> 4;
        const int mN = s & 15;
        const int nc = mN << 3;
        const float* src = &Wf[(size_t)(k0 + kr) * D_DIM + n0 + nc];
        f32x4 w0 = *(const f32x4*)src;
        f32x4 w1 = *(const f32x4*)(src + 4);
        const int cb = (((kr >> 3) ^ (mN & 3)) << 3) + (kr & 7);
#pragma unroll
        for (int j = 0; j < 4; ++j) {
          Bs[(nc + j) * 40 + cb] = f2bf(w0[j]);
          Bs[(nc + 4 + j) * 40 + cb] = f2bf(w1[j]);
        }
      }
    }
    __syncthreads();
    u32x4 af[4], bfr[4];
#pragma unroll
    for (int mi = 0; mi < 4; ++mi)
      af[mi] = *(const u32x4*)&As[(wr * 64 + mi * 16 + lr) * 40 + lg * 8];
#pragma unroll
    for (int ni = 0; ni < 4; ++ni) {
      const int row = wc * 64 + ni * 16 + lr;
      if (BPRE)
        bfr[ni] = *(const u32x4*)&Bs[row * 40 + lg * 8];
      else
        bfr[ni] = *(const u32x4*)&Bs[row * 40 + ((lg ^ ((row >> 3) & 3)) << 3)];
    }
#pragma unroll
    for (int mi = 0; mi < 4; ++mi)
#pragma unroll
      for (int ni = 0; ni < 4; ++ni)
        acc[mi][ni] = mfma16(af[mi], bfr[ni], acc[mi][ni]);
  }

#pragma unroll
  for (int ni = 0; ni < 4; ++ni) {
    const int n = n0 + wc * 64 + ni * 16 + lr;
    const float bv = bias[n];
#pragma unroll
    for (int mi = 0; mi < 4; ++mi) {
      const int mb = m0 + wr * 64 + mi * 16 + lg * 4;
      if (epi == 2) {  // V^T: [B][H][DK][S]
        const int bb = mb >> 11, ss = mb & (S_LEN - 1);
        const int hh = n >> 6, dd = n & (DK - 1);
        union { u16 u[4]; unsigned long long q; } pk;
#pragma unroll
        for (int r = 0; r < 4; ++r) pk.u[r] = f2bf((acc[mi][ni][r] + bv) * osc);
        *(unsigned long long*)&((u16*)dstv)[((size_t)((bb * N_HEADS + hh) * DK + dd)) * S_LEN + ss] = pk.q;
      } else {
#pragma unroll
        for (int r = 0; r < 4; ++r) {
          const int m = mb + r;
          const float o = (acc[mi][ni][r] + bv) * osc;
          if (epi == 1) {
            const int bb = m >> 11, ss = m & (S_LEN - 1);
            const int hh = n >> 6, dd = n & (DK - 1);
            ((u16*)dstv)[(((size_t)(bb * N_HEADS + hh) * S_LEN) + ss) * DK + dd] = f2bf(o);
          } else {
            ((float*)dstv)[(size_t)m * D_DIM + n] = o;
          }
        }
      }
    }
  }
}

// ---- causal flash attention, KVBLK=64, XCD-pinned heads ---------------------
// 1-D grid of 2048 blocks. Decode pins all 32 q-tiles of one (b,h) to one
// XCD (id&7 == bh&7, dispatch round-robins linear id across XCDs): per-XCD
// working set = 8 heads x 512KB K+V = 4MB = L2 size -> K/V loads become L2
// hits, shortening the exposed latency chain (round-5/6 diagnosis).
// Body = round-5 structure: Vt LDS double-buffer (coalesced cooperative
// staging), K/V register prefetch, 1 barrier/tile, no-max exp2 softmax,
// deferred row-sum.
__global__ __launch_bounds__(256) void attn_kernel(const u16* __restrict__ Qb,
                                                   const u16* __restrict__ Kb,
                                                   const u16* __restrict__ VTb,
                                                   u16* __restrict__ Xb) {
  __shared__ __align__(16) u16 Vt[2][64 * 64];   // [buf][dk][kp], chunk-swizzled
  __shared__ __align__(16) u16 Pl[4][16 * 72];   // per-wave [q_local][kpos]

  const int tid = threadIdx.x;
  const int lane = tid & 63;
  const int w = tid >> 6;
  const int lr = lane & 15;
  const int lg = lane >> 4;

  // XCD-pinning decode: id = (bh_hi*32 + qi)*8 + (bh&7)
  const int id = (int)blockIdx.x;
  const int xcd = id & 7;
  const int slot = id >> 3;
  const int bh = ((slot >> 5) << 3) | xcd;
  const int qi = slot & 31;
  const int q0 = (31 - qi) * 64;        // heavy-first within each head
  const int h = bh & (N_HEADS - 1);
  const int b = bh >> 4;

  const u16* Qh = Qb + ((size_t)bh) * S_LEN * DK;
  const u16* Kh = Kb + ((size_t)bh) * S_LEN * DK;
  const u16* VTh = VTb + ((size_t)bh) * DK * S_LEN;

  const int qrow_base = q0 + w * 16 + lg * 4;
  const int nt = (q0 >> 6) + 1;

  const int vdk = tid >> 3;        // V staging: rows vdk, vdk+32
  const int vc = tid & 7;          // 16B chunk

  u32x4 qf[2];
#pragma unroll
  for (int g = 0; g < 2; ++g)
    qf[g] = *(const u32x4*)&Qh[(size_t)(q0 + w * 16 + lr) * DK + g * 32 + lg * 8];

  f32x4 xacc[4];
#pragma unroll
  for (int i = 0; i < 4; ++i) xacc[i] = (f32x4){0.f, 0.f, 0.f, 0.f};
  float plsum[4] = {0.f, 0.f, 0.f, 0.f};

  // prologue: stage V(0) into buf0; prefetch K(0)
  u32x4 vpre[2], kreg[8];
#pragma unroll
  for (int i = 0; i < 2; ++i)
    vpre[i] = *(const u32x4*)&VTh[(size_t)(vdk + i * 32) * S_LEN + vc * 8];
#pragma unroll
  for (int g = 0; g < 2; ++g)
#pragma unroll
    for (int tt = 0; tt < 4; ++tt)
      kreg[g * 4 + tt] = *(const u32x4*)&Kh[(size_t)(tt * 16 + lr) * DK + g * 32 + lg * 8];
#pragma unroll
  for (int i = 0; i < 2; ++i) {
    const int dk = vdk + i * 32;
    *(u32x4*)&Vt[0][dk * 64 + ((vc ^ (dk & 7)) << 3)] = vpre[i];
  }

  for (int t = 0; t < nt; ++t) {
    const int kp0 = t << 6;
    // QK^T (consumes kreg for tile t)
    f32x4 sc[4];
#pragma unroll
    for (int tt = 0; tt < 4; ++tt) sc[tt] = (f32x4){0.f, 0.f, 0.f, 0.f};
    __builtin_amdgcn_s_setprio(1);
#pragma unroll
    for (int g = 0; g < 2; ++g)
#pragma unroll
      for (int tt = 0; tt < 4; ++tt)
        sc[tt] = mfma16(qf[g], kreg[g * 4 + tt], sc[tt]);
    __builtin_amdgcn_s_setprio(0);
    // prefetch K(t+1), V(t+1) (clamped; redundant loads on last iter)
    const int tn = (t + 1 < nt) ? t + 1 : t;
#pragma unroll
    for (int g = 0; g < 2; ++g)
#pragma unroll
      for (int tt = 0; tt < 4; ++tt)
        kreg[g * 4 + tt] = *(const u32x4*)&Kh[(size_t)((tn << 6) + tt * 16 + lr) * DK + g * 32 + lg * 8];
#pragma unroll
    for (int i = 0; i < 2; ++i)
      vpre[i] = *(const u32x4*)&VTh[(size_t)(vdk + i * 32) * S_LEN + (tn << 6) + vc * 8];
    // softmax: p = exp2(s), masked to 0; per-lane partial sums only
    float pp[4][4];
#pragma unroll
    for (int tt = 0; tt < 4; ++tt)
#pragma unroll
      for (int r = 0; r < 4; ++r) {
        const float e = exp2f(sc[tt][r]);
        const float p = (kp0 + tt * 16 + lr > qrow_base + r) ? 0.f : e;
        pp[tt][r] = p;
        plsum[r] += p;
      }
#pragma unroll
    for (int r = 0; r < 4; ++r)
#pragma unroll
      for (int tt = 0; tt < 4; ++tt)
        Pl[w][(lg * 4 + r) * 72 + tt * 16 + lr] = f2bf(pp[tt][r]);
    __syncthreads();
    // PV from Vt[t&1]
    u32x4 pf0 = *(const u32x4*)&Pl[w][lr * 72 + lg * 8];
    u32x4 pf1 = *(const u32x4*)&Pl[w][lr * 72 + 32 + lg * 8];
    __builtin_amdgcn_s_setprio(1);
#pragma unroll
    for (int db = 0; db < 4; ++db) {
      const int vrow = db * 16 + lr;
      u32x4 vf0 = *(const u32x4*)&Vt[t & 1][vrow * 64 + ((lg ^ (vrow & 7)) << 3)];
      u32x4 vf1 = *(const u32x4*)&Vt[t & 1][vrow * 64 + (((lg ^ 4) ^ (vrow & 7)) << 3)];
      xacc[db] = mfma16(pf0, vf0, xacc[db]);
      xacc[db] = mfma16(pf1, vf1, xacc[db]);
    }
    __builtin_amdgcn_s_setprio(0);
    // stage V(t+1) into the other buffer (write-after-barrier, read after
    // the NEXT barrier — ordered)
#pragma unroll
    for (int i = 0; i < 2; ++i) {
      const int dk = vdk + i * 32;
      *(u32x4*)&Vt[(t + 1) & 1][dk * 64 + ((vc ^ (dk & 7)) << 3)] = vpre[i];
    }
  }

  // deferred row-sum reduction (once per kernel)
#pragma unroll
  for (int d = 1; d < 16; d <<= 1)
#pragma unroll
    for (int r = 0; r < 4; ++r) plsum[r] += __shfl_xor(plsum[r], d);

#pragma unroll
  for (int r = 0; r < 4; ++r) {
    const float inv = 1.0f / fmaxf(plsum[r], 1e-30f);
    const int srow = qrow_base + r;
    const size_t base = ((size_t)b * S_LEN + srow) * D_DIM + h * DK;
#pragma unroll
    for (int db = 0; db < 4; ++db)
      Xb[base + db * 16 + lr] = f2bf(xacc[db][r] * inv);
  }
}

// ---- launcher ---------------------------------------------------------------
// d_out holds Qb+Kb (bf16, 33.55MB = out_size*4B). ws: VTb + Xb (+4x WT bf16).
extern "C" void kernel_launch(void* const* d_in, const int* in_sizes, int n_in,
                              void* d_out, int out_size, void* d_ws, size_t ws_size,
                              hipStream_t stream) {
  const float* q = (const float*)d_in[0];
  const float* k = (const float*)d_in[1];
  const float* v = (const float*)d_in[2];
  const float* Wq = (const float*)d_in[4];  const float* bq = (const float*)d_in[5];
  const float* Wk = (const float*)d_in[6];  const float* bk = (const float*)d_in[7];
  const float* Wv = (const float*)d_in[8];  const float* bv = (const float*)d_in[9];
  const float* Wo = (const float*)d_in[10]; const float* bo = (const float*)d_in[11];

  u16* Qb = (u16*)d_out;
  u16* Kb = Qb + (8u << 20);
  u16* VTb = (u16*)d_ws;
  u16* Xb = VTb + (8u << 20);

  const float scl = 0.125f * 1.4426950408889634f;  // 1/sqrt(DK) * log2(e)
  const dim3 tb(256);
  const size_t need = ((size_t)(8u << 20)) * 2 * 2 + 4 * ((size_t)(1u << 20)) * 2;

  if (ws_size >= need) {
    u16* WqT = Xb + (8u << 20);
    u16* WkT = WqT + (1u << 20);
    u16* WvT = WkT + (1u << 20);
    u16* WoT = WvT + (1u << 20);
    transpose_wf<<<dim3(32, 32), tb, 0, stream>>>(Wq, WqT);
    transpose_wf<<<dim3(32, 32), tb, 0, stream>>>(Wk, WkT);
    transpose_wf<<<dim3(32, 32), tb, 0, stream>>>(Wv, WvT);
    transpose_wf<<<dim3(32, 32), tb, 0, stream>>>(Wo, WoT);
    gemm_xw<1, 1><<<dim3(64, 8), tb, 0, stream>>>(q, WqT, bq, Qb, 1, scl);
    gemm_xw<1, 1><<<dim3(64, 8), tb, 0, stream>>>(k, WkT, bk, Kb, 1, 1.0f);
    gemm_xw<1, 1><<<dim3(64, 8), tb, 0, stream>>>(v, WvT, bv, VTb, 2, 1.0f);
    attn_kernel<<<dim3(2048), tb, 0, stream>>>(Qb, Kb, VTb, Xb);
    gemm_xw<0, 1><<<dim3(64, 8), tb, 0, stream>>>(Xb, WoT, bo, d_out, 0, 1.0f);
  } else {
    gemm_xw<1, 0><<<dim3(64, 8), tb, 0, stream>>>(q, Wq, bq, Qb, 1, scl);
    gemm_xw<1, 0><<<dim3(64, 8), tb, 0, stream>>>(k, Wk, bk, Kb, 1, 1.0f);
    gemm_xw<1, 0><<<dim3(64, 8), tb, 0, stream>>>(v, Wv, bv, VTb, 2, 1.0f);
    attn_kernel<<<dim3(2048), tb, 0, stream>>>(Qb, Kb, VTb, Xb);
    gemm_xw<0, 0><<<dim3(64, 8), tb, 0, stream>>>(Xb, Wo, bo, d_out, 0, 1.0f);
  }
}

// Round 8
// 293.127 us; speedup vs baseline: 2.0937x; 1.1470x over previous
//
#include <hip/hip_runtime.h>

typedef unsigned short u16;
typedef __attribute__((ext_vector_type(4))) float f32x4;
typedef __attribute__((ext_vector_type(8))) __bf16 bf16x8;
typedef __attribute__((ext_vector_type(4))) unsigned int u32x4;

#define S_LEN 2048
#define D_DIM 1024
#define N_HEADS 16
#define DK 64
#define B_SZ 4

__device__ __forceinline__ u16 f2bf(float f) {
  unsigned int u = __float_as_uint(f);
  unsigned int r = (u + 0x7FFFu + ((u >> 16) & 1u)) >> 16;
  return (u16)r;
}
__device__ __forceinline__ f32x4 mfma16(u32x4 a, u32x4 b, f32x4 c) {
  return __builtin_amdgcn_mfma_f32_16x16x32_bf16(
      __builtin_bit_cast(bf16x8, a), __builtin_bit_cast(bf16x8, b), c, 0, 0, 0);
}

// ---- weight transpose+convert: WT[n][k] (bf16) = W[k][n] (f32) -------------
__global__ __launch_bounds__(256) void transpose_wf(const float* __restrict__ W,
                                                    u16* __restrict__ WT) {
  __shared__ float tb[32][33];
  const int tx = threadIdx.x & 31;
  const int ty0 = (threadIdx.x >> 5) << 2;
  const int bn = blockIdx.x << 5;
  const int bk = blockIdx.y << 5;
#pragma unroll
  for (int i = 0; i < 4; ++i)
    tb[ty0 + i][tx] = W[(size_t)(bk + ty0 + i) * D_DIM + bn + tx];
  __syncthreads();
#pragma unroll
  for (int i = 0; i < 4; ++i)
    WT[(size_t)(bn + ty0 + i) * D_DIM + bk + tx] = f2bf(tb[tx][ty0 + i]);
}

// ---- GEMM: dst = X[8192x1024] @ W + bias ------------------------------------
// (unchanged from round 6/7 — ~35us each with BPRE path)
template <int AF32, int BPRE>
__global__ __launch_bounds__(256) void gemm_xw(const void* __restrict__ Av,
                                               const void* __restrict__ Bv,
                                               const float* __restrict__ bias,
                                               void* __restrict__ dstv,
                                               const int epi, const float osc) {
  __shared__ __align__(16) u16 As[128 * 40];
  __shared__ __align__(16) u16 Bs[128 * 40];
  const int tid = threadIdx.x;
  const int lane = tid & 63;
  const int wid = tid >> 6;
  const int wr = wid >> 1, wc = wid & 1;
  const int lr = lane & 15, lg = lane >> 4;
  const int m0 = blockIdx.x * 128;
  const int n0 = blockIdx.y * 128;

  const float* Xf = (const float*)Av;
  const u16* Xh = (const u16*)Av;
  const float* Wf = (const float*)Bv;
  const u16* WT = (const u16*)Bv;

  f32x4 acc[4][4];
#pragma unroll
  for (int i = 0; i < 4; ++i)
#pragma unroll
    for (int j = 0; j < 4; ++j) acc[i][j] = (f32x4){0.f, 0.f, 0.f, 0.f};

  const int srow = tid >> 2;
  const int sko = (tid & 3) << 3;

  for (int k0 = 0; k0 < D_DIM; k0 += 32) {
    __syncthreads();
#pragma unroll
    for (int i = 0; i < 2; ++i) {
      const int row = srow + i * 64;
      union { u32x4 v; u16 u[8]; } pk;
      if (AF32) {
        const float* src = &Xf[(size_t)(m0 + row) * D_DIM + k0 + sko];
        f32x4 a0 = *(const f32x4*)src;
        f32x4 a1 = *(const f32x4*)(src + 4);
#pragma unroll
        for (int j = 0; j < 4; ++j) { pk.u[j] = f2bf(a0[j]); pk.u[4 + j] = f2bf(a1[j]); }
      } else {
        pk.v = *(const u32x4*)&Xh[(size_t)(m0 + row) * D_DIM + k0 + sko];
      }
      *(u32x4*)&As[row * 40 + sko] = pk.v;
    }
    if (BPRE) {
#pragma unroll
      for (int i = 0; i < 2; ++i) {
        const int row = srow + i * 64;
        u32x4 bch = *(const u32x4*)&WT[(size_t)(n0 + row) * D_DIM + k0 + sko];
        *(u32x4*)&Bs[row * 40 + sko] = bch;
      }
    } else {
#pragma unroll
      for (int i = 0; i < 2; ++i) {
        const int s = tid + (i << 8);
        const int kr = s >> 4;
        const int mN = s & 15;
        const int nc = mN << 3;
        const float* src = &Wf[(size_t)(k0 + kr) * D_DIM + n0 + nc];
        f32x4 w0 = *(const f32x4*)src;
        f32x4 w1 = *(const f32x4*)(src + 4);
        const int cb = (((kr >> 3) ^ (mN & 3)) << 3) + (kr & 7);
#pragma unroll
        for (int j = 0; j < 4; ++j) {
          Bs[(nc + j) * 40 + cb] = f2bf(w0[j]);
          Bs[(nc + 4 + j) * 40 + cb] = f2bf(w1[j]);
        }
      }
    }
    __syncthreads();
    u32x4 af[4], bfr[4];
#pragma unroll
    for (int mi = 0; mi < 4; ++mi)
      af[mi] = *(const u32x4*)&As[(wr * 64 + mi * 16 + lr) * 40 + lg * 8];
#pragma unroll
    for (int ni = 0; ni < 4; ++ni) {
      const int row = wc * 64 + ni * 16 + lr;
      if (BPRE)
        bfr[ni] = *(const u32x4*)&Bs[row * 40 + lg * 8];
      else
        bfr[ni] = *(const u32x4*)&Bs[row * 40 + ((lg ^ ((row >> 3) & 3)) << 3)];
    }
#pragma unroll
    for (int mi = 0; mi < 4; ++mi)
#pragma unroll
      for (int ni = 0; ni < 4; ++ni)
        acc[mi][ni] = mfma16(af[mi], bfr[ni], acc[mi][ni]);
  }

#pragma unroll
  for (int ni = 0; ni < 4; ++ni) {
    const int n = n0 + wc * 64 + ni * 16 + lr;
    const float bv = bias[n];
#pragma unroll
    for (int mi = 0; mi < 4; ++mi) {
      const int mb = m0 + wr * 64 + mi * 16 + lg * 4;
      if (epi == 2) {  // V^T: [B][H][DK][S]
        const int bb = mb >> 11, ss = mb & (S_LEN - 1);
        const int hh = n >> 6, dd = n & (DK - 1);
        union { u16 u[4]; unsigned long long q; } pk;
#pragma unroll
        for (int r = 0; r < 4; ++r) pk.u[r] = f2bf((acc[mi][ni][r] + bv) * osc);
        *(unsigned long long*)&((u16*)dstv)[((size_t)((bb * N_HEADS + hh) * DK + dd)) * S_LEN + ss] = pk.q;
      } else {
#pragma unroll
        for (int r = 0; r < 4; ++r) {
          const int m = mb + r;
          const float o = (acc[mi][ni][r] + bv) * osc;
          if (epi == 1) {
            const int bb = m >> 11, ss = m & (S_LEN - 1);
            const int hh = n >> 6, dd = n & (DK - 1);
            ((u16*)dstv)[(((size_t)(bb * N_HEADS + hh) * S_LEN) + ss) * DK + dd] = f2bf(o);
          } else {
            ((float*)dstv)[(size_t)m * D_DIM + n] = o;
          }
        }
      }
    }
  }
}

// ---- causal flash attention, QBLK=128, KVBLK=64, XCD-pinned heads -----------
// 1-D grid of 1024 blocks; 4 waves; wave w owns 32 q-rows (two 16-row MFMA
// subtiles m=0,1). Doubling q-rows/wave amortizes the per-tile serial chain
// (K/V prefetch, V-stage, barrier, P-read) over 2x MFMA+softmax work
// (round-7 diagnosis: latency-bound at MfmaUtil 7.7%).
// XCD pinning: all 16 q-tiles of one (b,h) on one XCD; 8 heads/XCD -> 4MB
// K+V working set = L2 size (round-7: FETCH 144->24.6MB).
__global__ __launch_bounds__(256) void attn_kernel(const u16* __restrict__ Qb,
                                                   const u16* __restrict__ Kb,
                                                   const u16* __restrict__ VTb,
                                                   u16* __restrict__ Xb) {
  __shared__ __align__(16) u16 Vt[2][64 * 64];   // [buf][dk][kp], chunk-swizzled
  __shared__ __align__(16) u16 Pl[4][32 * 72];   // per-wave [q_local 0..31][kpos]

  const int tid = threadIdx.x;
  const int lane = tid & 63;
  const int w = tid >> 6;
  const int lr = lane & 15;
  const int lg = lane >> 4;

  // XCD-pinning decode: id = (bh_hi*16 + qi)*8 + (bh&7)
  const int id = (int)blockIdx.x;
  const int xcd = id & 7;
  const int slot = id >> 3;
  const int bh = ((slot >> 4) << 3) | xcd;
  const int qi = slot & 15;
  const int q0 = (15 - qi) * 128;        // heavy-first within each head
  const int h = bh & (N_HEADS - 1);
  const int b = bh >> 4;

  const u16* Qh = Qb + ((size_t)bh) * S_LEN * DK;
  const u16* Kh = Kb + ((size_t)bh) * S_LEN * DK;
  const u16* VTh = VTb + ((size_t)bh) * DK * S_LEN;

  const int wrow = q0 + w * 32;          // wave's first q row
  const int nt = (q0 >> 6) + 2;          // 64-kpos tiles to cover q0+127

  const int vdk = tid >> 3;        // V staging: rows vdk, vdk+32
  const int vc = tid & 7;          // 16B chunk

  u32x4 qf[2][2];
#pragma unroll
  for (int m = 0; m < 2; ++m)
#pragma unroll
    for (int g = 0; g < 2; ++g)
      qf[m][g] = *(const u32x4*)&Qh[(size_t)(wrow + m * 16 + lr) * DK + g * 32 + lg * 8];

  f32x4 xacc[2][4];
#pragma unroll
  for (int m = 0; m < 2; ++m)
#pragma unroll
    for (int i = 0; i < 4; ++i) xacc[m][i] = (f32x4){0.f, 0.f, 0.f, 0.f};
  float plsum[2][4] = {{0.f, 0.f, 0.f, 0.f}, {0.f, 0.f, 0.f, 0.f}};

  // prologue: stage V(0) into buf0; prefetch K(0)
  u32x4 vpre[2], kreg[8];
#pragma unroll
  for (int i = 0; i < 2; ++i)
    vpre[i] = *(const u32x4*)&VTh[(size_t)(vdk + i * 32) * S_LEN + vc * 8];
#pragma unroll
  for (int g = 0; g < 2; ++g)
#pragma unroll
    for (int tt = 0; tt < 4; ++tt)
      kreg[g * 4 + tt] = *(const u32x4*)&Kh[(size_t)(tt * 16 + lr) * DK + g * 32 + lg * 8];
#pragma unroll
  for (int i = 0; i < 2; ++i) {
    const int dk = vdk + i * 32;
    *(u32x4*)&Vt[0][dk * 64 + ((vc ^ (dk & 7)) << 3)] = vpre[i];
  }

  for (int t = 0; t < nt; ++t) {
    const int kp0 = t << 6;
    // QK^T for both 16-row subtiles (consumes kreg for tile t)
    f32x4 sc[2][4];
#pragma unroll
    for (int m = 0; m < 2; ++m)
#pragma unroll
      for (int tt = 0; tt < 4; ++tt) sc[m][tt] = (f32x4){0.f, 0.f, 0.f, 0.f};
    __builtin_amdgcn_s_setprio(1);
#pragma unroll
    for (int g = 0; g < 2; ++g)
#pragma unroll
      for (int tt = 0; tt < 4; ++tt) {
        sc[0][tt] = mfma16(qf[0][g], kreg[g * 4 + tt], sc[0][tt]);
        sc[1][tt] = mfma16(qf[1][g], kreg[g * 4 + tt], sc[1][tt]);
      }
    __builtin_amdgcn_s_setprio(0);
    // prefetch K(t+1), V(t+1) (clamped; redundant loads on last iter)
    const int tn = (t + 1 < nt) ? t + 1 : t;
#pragma unroll
    for (int g = 0; g < 2; ++g)
#pragma unroll
      for (int tt = 0; tt < 4; ++tt)
        kreg[g * 4 + tt] = *(const u32x4*)&Kh[(size_t)((tn << 6) + tt * 16 + lr) * DK + g * 32 + lg * 8];
#pragma unroll
    for (int i = 0; i < 2; ++i)
      vpre[i] = *(const u32x4*)&VTh[(size_t)(vdk + i * 32) * S_LEN + (tn << 6) + vc * 8];
    // no-max softmax: p = exp2(s) masked to 0; per-lane partials only
#pragma unroll
    for (int m = 0; m < 2; ++m) {
      const int qrb = wrow + m * 16 + lg * 4;
#pragma unroll
      for (int tt = 0; tt < 4; ++tt)
#pragma unroll
        for (int r = 0; r < 4; ++r) {
          const float e = exp2f(sc[m][tt][r]);
          const float p = (kp0 + tt * 16 + lr > qrb + r) ? 0.f : e;
          plsum[m][r] += p;
          Pl[w][(m * 16 + lg * 4 + r) * 72 + tt * 16 + lr] = f2bf(p);
        }
    }
    __syncthreads();
    // PV from Vt[t&1] for both subtiles
    u32x4 pf[2][2];
#pragma unroll
    for (int m = 0; m < 2; ++m) {
      pf[m][0] = *(const u32x4*)&Pl[w][(m * 16 + lr) * 72 + lg * 8];
      pf[m][1] = *(const u32x4*)&Pl[w][(m * 16 + lr) * 72 + 32 + lg * 8];
    }
    __builtin_amdgcn_s_setprio(1);
#pragma unroll
    for (int db = 0; db < 4; ++db) {
      const int vrow = db * 16 + lr;
      u32x4 vf0 = *(const u32x4*)&Vt[t & 1][vrow * 64 + ((lg ^ (vrow & 7)) << 3)];
      u32x4 vf1 = *(const u32x4*)&Vt[t & 1][vrow * 64 + (((lg ^ 4) ^ (vrow & 7)) << 3)];
#pragma unroll
      for (int m = 0; m < 2; ++m) {
        xacc[m][db] = mfma16(pf[m][0], vf0, xacc[m][db]);
        xacc[m][db] = mfma16(pf[m][1], vf1, xacc[m][db]);
      }
    }
    __builtin_amdgcn_s_setprio(0);
    // stage V(t+1) into the other buffer (write-after-barrier, read after
    // the NEXT barrier — ordered)
#pragma unroll
    for (int i = 0; i < 2; ++i) {
      const int dk = vdk + i * 32;
      *(u32x4*)&Vt[(t + 1) & 1][dk * 64 + ((vc ^ (dk & 7)) << 3)] = vpre[i];
    }
  }

  // deferred row-sum reduction (once per kernel)
#pragma unroll
  for (int d = 1; d < 16; d <<= 1)
#pragma unroll
    for (int m = 0; m < 2; ++m)
#pragma unroll
      for (int r = 0; r < 4; ++r) plsum[m][r] += __shfl_xor(plsum[m][r], d);

#pragma unroll
  for (int m = 0; m < 2; ++m)
#pragma unroll
    for (int r = 0; r < 4; ++r) {
      const float inv = 1.0f / fmaxf(plsum[m][r], 1e-30f);
      const int srow = wrow + m * 16 + lg * 4 + r;
      const size_t base = ((size_t)b * S_LEN + srow) * D_DIM + h * DK;
#pragma unroll
      for (int db = 0; db < 4; ++db)
        Xb[base + db * 16 + lr] = f2bf(xacc[m][db][r] * inv);
    }
}

// ---- launcher ---------------------------------------------------------------
// d_out holds Qb+Kb (bf16, 33.55MB = out_size*4B). ws: VTb + Xb (+4x WT bf16).
extern "C" void kernel_launch(void* const* d_in, const int* in_sizes, int n_in,
                              void* d_out, int out_size, void* d_ws, size_t ws_size,
                              hipStream_t stream) {
  const float* q = (const float*)d_in[0];
  const float* k = (const float*)d_in[1];
  const float* v = (const float*)d_in[2];
  const float* Wq = (const float*)d_in[4];  const float* bq = (const float*)d_in[5];
  const float* Wk = (const float*)d_in[6];  const float* bk = (const float*)d_in[7];
  const float* Wv = (const float*)d_in[8];  const float* bv = (const float*)d_in[9];
  const float* Wo = (const float*)d_in[10]; const float* bo = (const float*)d_in[11];

  u16* Qb = (u16*)d_out;
  u16* Kb = Qb + (8u << 20);
  u16* VTb = (u16*)d_ws;
  u16* Xb = VTb + (8u << 20);

  const float scl = 0.125f * 1.4426950408889634f;  // 1/sqrt(DK) * log2(e)
  const dim3 tb(256);
  const size_t need = ((size_t)(8u << 20)) * 2 * 2 + 4 * ((size_t)(1u << 20)) * 2;

  if (ws_size >= need) {
    u16* WqT = Xb + (8u << 20);
    u16* WkT = WqT + (1u << 20);
    u16* WvT = WkT + (1u << 20);
    u16* WoT = WvT + (1u << 20);
    transpose_wf<<<dim3(32, 32), tb, 0, stream>>>(Wq, WqT);
    transpose_wf<<<dim3(32, 32), tb, 0, stream>>>(Wk, WkT);
    transpose_wf<<<dim3(32, 32), tb, 0, stream>>>(Wv, WvT);
    transpose_wf<<<dim3(32, 32), tb, 0, stream>>>(Wo, WoT);
    gemm_xw<1, 1><<<dim3(64, 8), tb, 0, stream>>>(q, WqT, bq, Qb, 1, scl);
    gemm_xw<1, 1><<<dim3(64, 8), tb, 0, stream>>>(k, WkT, bk, Kb, 1, 1.0f);
    gemm_xw<1, 1><<<dim3(64, 8), tb, 0, stream>>>(v, WvT, bv, VTb, 2, 1.0f);
    attn_kernel<<<dim3(1024), tb, 0, stream>>>(Qb, Kb, VTb, Xb);
    gemm_xw<0, 1><<<dim3(64, 8), tb, 0, stream>>>(Xb, WoT, bo, d_out, 0, 1.0f);
  } else {
    gemm_xw<1, 0><<<dim3(64, 8), tb, 0, stream>>>(q, Wq, bq, Qb, 1, scl);
    gemm_xw<1, 0><<<dim3(64, 8), tb, 0, stream>>>(k, Wk, bk, Kb, 1, 1.0f);
    gemm_xw<1, 0><<<dim3(64, 8), tb, 0, stream>>>(v, Wv, bv, VTb, 2, 1.0f);
    attn_kernel<<<dim3(1024), tb, 0, stream>>>(Qb, Kb, VTb, Xb);
    gemm_xw<0, 0><<<dim3(64, 8), tb, 0, stream>>>(Xb, Wo, bo, d_out, 0, 1.0f);
  }
}

// Round 9
// 272.027 us; speedup vs baseline: 2.2561x; 1.0776x over previous
//
#include <hip/hip_runtime.h>

typedef unsigned short u16;
typedef __attribute__((ext_vector_type(4))) float f32x4;
typedef __attribute__((ext_vector_type(8))) __bf16 bf16x8;
typedef __attribute__((ext_vector_type(4))) unsigned int u32x4;

#define S_LEN 2048
#define D_DIM 1024
#define N_HEADS 16
#define DK 64
#define B_SZ 4

__device__ __forceinline__ u16 f2bf(float f) {
  unsigned int u = __float_as_uint(f);
  unsigned int r = (u + 0x7FFFu + ((u >> 16) & 1u)) >> 16;
  return (u16)r;
}
__device__ __forceinline__ unsigned int cvtpk(float a, float b) {
  unsigned int r;
  asm("v_cvt_pk_bf16_f32 %0, %1, %2" : "=v"(r) : "v"(a), "v"(b));
  return r;  // low16 = bf16(a), high16 = bf16(b)
}
__device__ __forceinline__ f32x4 mfma16(u32x4 a, u32x4 b, f32x4 c) {
  return __builtin_amdgcn_mfma_f32_16x16x32_bf16(
      __builtin_bit_cast(bf16x8, a), __builtin_bit_cast(bf16x8, b), c, 0, 0, 0);
}

// ---- fused weight transposes: WT[n][k] (bf16) = W[k][n] (f32), z = which ---
__global__ __launch_bounds__(256) void transpose_all(
    const float* __restrict__ W0, const float* __restrict__ W1,
    const float* __restrict__ W2, const float* __restrict__ W3,
    u16* __restrict__ T0, u16* __restrict__ T1,
    u16* __restrict__ T2, u16* __restrict__ T3) {
  __shared__ float tb[32][33];
  const int z = blockIdx.z;
  const float* W = (z == 0) ? W0 : (z == 1) ? W1 : (z == 2) ? W2 : W3;
  u16* WT = (z == 0) ? T0 : (z == 1) ? T1 : (z == 2) ? T2 : T3;
  const int tx = threadIdx.x & 31;
  const int ty0 = (threadIdx.x >> 5) << 2;
  const int bn = blockIdx.x << 5;
  const int bk = blockIdx.y << 5;
#pragma unroll
  for (int i = 0; i < 4; ++i)
    tb[ty0 + i][tx] = W[(size_t)(bk + ty0 + i) * D_DIM + bn + tx];
  __syncthreads();
#pragma unroll
  for (int i = 0; i < 4; ++i)
    WT[(size_t)(bn + ty0 + i) * D_DIM + bk + tx] = f2bf(tb[tx][ty0 + i]);
}

// ---- GEMM: dst = X[8192x1024] @ W + bias (unchanged round-7 structure) -----
template <int AF32, int BPRE>
__global__ __launch_bounds__(256) void gemm_xw(const void* __restrict__ Av,
                                               const void* __restrict__ Bv,
                                               const float* __restrict__ bias,
                                               void* __restrict__ dstv,
                                               const int epi, const float osc) {
  __shared__ __align__(16) u16 As[128 * 40];
  __shared__ __align__(16) u16 Bs[128 * 40];
  const int tid = threadIdx.x;
  const int lane = tid & 63;
  const int wid = tid >> 6;
  const int wr = wid >> 1, wc = wid & 1;
  const int lr = lane & 15, lg = lane >> 4;
  const int m0 = blockIdx.x * 128;
  const int n0 = blockIdx.y * 128;

  const float* Xf = (const float*)Av;
  const u16* Xh = (const u16*)Av;
  const float* Wf = (const float*)Bv;
  const u16* WT = (const u16*)Bv;

  f32x4 acc[4][4];
#pragma unroll
  for (int i = 0; i < 4; ++i)
#pragma unroll
    for (int j = 0; j < 4; ++j) acc[i][j] = (f32x4){0.f, 0.f, 0.f, 0.f};

  const int srow = tid >> 2;
  const int sko = (tid & 3) << 3;

  for (int k0 = 0; k0 < D_DIM; k0 += 32) {
    __syncthreads();
#pragma unroll
    for (int i = 0; i < 2; ++i) {
      const int row = srow + i * 64;
      union { u32x4 v; u16 u[8]; } pk;
      if (AF32) {
        const float* src = &Xf[(size_t)(m0 + row) * D_DIM + k0 + sko];
        f32x4 a0 = *(const f32x4*)src;
        f32x4 a1 = *(const f32x4*)(src + 4);
#pragma unroll
        for (int j = 0; j < 4; ++j) { pk.u[j] = f2bf(a0[j]); pk.u[4 + j] = f2bf(a1[j]); }
      } else {
        pk.v = *(const u32x4*)&Xh[(size_t)(m0 + row) * D_DIM + k0 + sko];
      }
      *(u32x4*)&As[row * 40 + sko] = pk.v;
    }
    if (BPRE) {
#pragma unroll
      for (int i = 0; i < 2; ++i) {
        const int row = srow + i * 64;
        u32x4 bch = *(const u32x4*)&WT[(size_t)(n0 + row) * D_DIM + k0 + sko];
        *(u32x4*)&Bs[row * 40 + sko] = bch;
      }
    } else {
#pragma unroll
      for (int i = 0; i < 2; ++i) {
        const int s = tid + (i << 8);
        const int kr = s >> 4;
        const int mN = s & 15;
        const int nc = mN << 3;
        const float* src = &Wf[(size_t)(k0 + kr) * D_DIM + n0 + nc];
        f32x4 w0 = *(const f32x4*)src;
        f32x4 w1 = *(const f32x4*)(src + 4);
        const int cb = (((kr >> 3) ^ (mN & 3)) << 3) + (kr & 7);
#pragma unroll
        for (int j = 0; j < 4; ++j) {
          Bs[(nc + j) * 40 + cb] = f2bf(w0[j]);
          Bs[(nc + 4 + j) * 40 + cb] = f2bf(w1[j]);
        }
      }
    }
    __syncthreads();
    u32x4 af[4], bfr[4];
#pragma unroll
    for (int mi = 0; mi < 4; ++mi)
      af[mi] = *(const u32x4*)&As[(wr * 64 + mi * 16 + lr) * 40 + lg * 8];
#pragma unroll
    for (int ni = 0; ni < 4; ++ni) {
      const int row = wc * 64 + ni * 16 + lr;
      if (BPRE)
        bfr[ni] = *(const u32x4*)&Bs[row * 40 + lg * 8];
      else
        bfr[ni] = *(const u32x4*)&Bs[row * 40 + ((lg ^ ((row >> 3) & 3)) << 3)];
    }
#pragma unroll
    for (int mi = 0; mi < 4; ++mi)
#pragma unroll
      for (int ni = 0; ni < 4; ++ni)
        acc[mi][ni] = mfma16(af[mi], bfr[ni], acc[mi][ni]);
  }

#pragma unroll
  for (int ni = 0; ni < 4; ++ni) {
    const int n = n0 + wc * 64 + ni * 16 + lr;
    const float bv = bias[n];
#pragma unroll
    for (int mi = 0; mi < 4; ++mi) {
      const int mb = m0 + wr * 64 + mi * 16 + lg * 4;
      if (epi == 2) {  // V^T: [B][H][DK][S]
        const int bb = mb >> 11, ss = mb & (S_LEN - 1);
        const int hh = n >> 6, dd = n & (DK - 1);
        union { u16 u[4]; unsigned long long q; } pk;
#pragma unroll
        for (int r = 0; r < 4; ++r) pk.u[r] = f2bf((acc[mi][ni][r] + bv) * osc);
        *(unsigned long long*)&((u16*)dstv)[((size_t)((bb * N_HEADS + hh) * DK + dd)) * S_LEN + ss] = pk.q;
      } else {
#pragma unroll
        for (int r = 0; r < 4; ++r) {
          const int m = mb + r;
          const float o = (acc[mi][ni][r] + bv) * osc;
          if (epi == 1) {
            const int bb = m >> 11, ss = m & (S_LEN - 1);
            const int hh = n >> 6, dd = n & (DK - 1);
            ((u16*)dstv)[(((size_t)(bb * N_HEADS + hh) * S_LEN) + ss) * DK + dd] = f2bf(o);
          } else {
            ((float*)dstv)[(size_t)m * D_DIM + n] = o;
          }
        }
      }
    }
  }
}

// ---- causal flash attention, QBLK=128/KVBLK=64, swapped QK^T, XCD-pinned ----
// Swapped score MFMA (mfma(K,Q)): lane holds P for q-row=lr, kpos=tt*16+lg*4+r
// -> consecutive-kpos pairs enable v_cvt_pk_bf16_f32 + ds_write_b64 (8 writes
// vs 32), and row-sum is one scalar/lane (2 shfl at end). Mask applied only on
// the diagonal tile (wave-uniform branch). Waves skip compute on fully-masked
// tiles but still co-stage V + barrier.
__global__ __launch_bounds__(256) void attn_kernel(const u16* __restrict__ Qb,
                                                   const u16* __restrict__ Kb,
                                                   const u16* __restrict__ VTb,
                                                   u16* __restrict__ Xb) {
  __shared__ __align__(16) u16 Vt[2][64 * 64];   // [buf][dk][kp], chunk-swizzled
  __shared__ __align__(16) u16 Pl[4][32 * 72];   // per-wave [q_local][kpos]

  const int tid = threadIdx.x;
  const int lane = tid & 63;
  const int w = tid >> 6;
  const int lr = lane & 15;
  const int lg = lane >> 4;

  // XCD-pinning decode: id = (bh_hi*16 + qi)*8 + (bh&7)
  const int id = (int)blockIdx.x;
  const int xcd = id & 7;
  const int slot = id >> 3;
  const int bh = ((slot >> 4) << 3) | xcd;
  const int qi = slot & 15;
  const int q0 = (15 - qi) * 128;        // heavy-first within each head
  const int h = bh & (N_HEADS - 1);
  const int b = bh >> 4;

  const u16* Qh = Qb + ((size_t)bh) * S_LEN * DK;
  const u16* Kh = Kb + ((size_t)bh) * S_LEN * DK;
  const u16* VTh = VTb + ((size_t)bh) * DK * S_LEN;

  const int wrow = q0 + w * 32;          // wave's first q row
  const int nt = (q0 >> 6) + 2;          // 64-kpos tiles covering q0+127

  const int vdk = tid >> 3;
  const int vc = tid & 7;

  u32x4 qf[2][2];
#pragma unroll
  for (int m = 0; m < 2; ++m)
#pragma unroll
    for (int g = 0; g < 2; ++g)
      qf[m][g] = *(const u32x4*)&Qh[(size_t)(wrow + m * 16 + lr) * DK + g * 32 + lg * 8];

  f32x4 xacc[2][4];
#pragma unroll
  for (int m = 0; m < 2; ++m)
#pragma unroll
    for (int i = 0; i < 4; ++i) xacc[m][i] = (f32x4){0.f, 0.f, 0.f, 0.f};
  float plsum[2] = {0.f, 0.f};           // per-lane partial sum for q-row lr

  u32x4 vpre[2], kreg[8];
#pragma unroll
  for (int i = 0; i < 2; ++i)
    vpre[i] = *(const u32x4*)&VTh[(size_t)(vdk + i * 32) * S_LEN + vc * 8];
#pragma unroll
  for (int g = 0; g < 2; ++g)
#pragma unroll
    for (int tt = 0; tt < 4; ++tt)
      kreg[g * 4 + tt] = *(const u32x4*)&Kh[(size_t)(tt * 16 + lr) * DK + g * 32 + lg * 8];
#pragma unroll
  for (int i = 0; i < 2; ++i) {
    const int dk = vdk + i * 32;
    *(u32x4*)&Vt[0][dk * 64 + ((vc ^ (dk & 7)) << 3)] = vpre[i];
  }

  for (int t = 0; t < nt; ++t) {
    const int kp0 = t << 6;
    const bool wact = (kp0 <= wrow + 31);
    const bool dmask = (kp0 + 63 > wrow);
    f32x4 sc[2][4];
#pragma unroll
    for (int m = 0; m < 2; ++m)
#pragma unroll
      for (int tt = 0; tt < 4; ++tt) sc[m][tt] = (f32x4){0.f, 0.f, 0.f, 0.f};
    if (wact) {
      __builtin_amdgcn_s_setprio(1);
#pragma unroll
      for (int g = 0; g < 2; ++g)
#pragma unroll
        for (int tt = 0; tt < 4; ++tt) {
          sc[0][tt] = mfma16(kreg[g * 4 + tt], qf[0][g], sc[0][tt]);  // swapped
          sc[1][tt] = mfma16(kreg[g * 4 + tt], qf[1][g], sc[1][tt]);
        }
      __builtin_amdgcn_s_setprio(0);
    }
    // prefetch K(t+1), V(t+1)
    const int tn = (t + 1 < nt) ? t + 1 : t;
#pragma unroll
    for (int g = 0; g < 2; ++g)
#pragma unroll
      for (int tt = 0; tt < 4; ++tt)
        kreg[g * 4 + tt] = *(const u32x4*)&Kh[(size_t)((tn << 6) + tt * 16 + lr) * DK + g * 32 + lg * 8];
#pragma unroll
    for (int i = 0; i < 2; ++i)
      vpre[i] = *(const u32x4*)&VTh[(size_t)(vdk + i * 32) * S_LEN + (tn << 6) + vc * 8];
    if (wact) {
      // softmax: p = exp2(s); mask only on diagonal tile; pack+b64-write
#pragma unroll
      for (int m = 0; m < 2; ++m) {
        const int qre = wrow + m * 16 + lr;       // this lane's q row
        float pv[4][4];
        if (dmask) {
#pragma unroll
          for (int tt = 0; tt < 4; ++tt)
#pragma unroll
            for (int r = 0; r < 4; ++r) {
              const int kpe = kp0 + tt * 16 + lg * 4 + r;
              float s = sc[m][tt][r];
              if (kpe > qre) s = -1e30f;
              pv[tt][r] = exp2f(s);
            }
        } else {
#pragma unroll
          for (int tt = 0; tt < 4; ++tt)
#pragma unroll
            for (int r = 0; r < 4; ++r) pv[tt][r] = exp2f(sc[m][tt][r]);
        }
#pragma unroll
        for (int tt = 0; tt < 4; ++tt) {
          plsum[m] += (pv[tt][0] + pv[tt][1]) + (pv[tt][2] + pv[tt][3]);
          uint2 pw;
          pw.x = cvtpk(pv[tt][0], pv[tt][1]);
          pw.y = cvtpk(pv[tt][2], pv[tt][3]);
          *(uint2*)&Pl[w][(m * 16 + lr) * 72 + tt * 16 + lg * 4] = pw;
        }
      }
    }
    __syncthreads();
    if (wact) {
      u32x4 pf[2][2];
#pragma unroll
      for (int m = 0; m < 2; ++m) {
        pf[m][0] = *(const u32x4*)&Pl[w][(m * 16 + lr) * 72 + lg * 8];
        pf[m][1] = *(const u32x4*)&Pl[w][(m * 16 + lr) * 72 + 32 + lg * 8];
      }
      __builtin_amdgcn_s_setprio(1);
#pragma unroll
      for (int db = 0; db < 4; ++db) {
        const int vrow = db * 16 + lr;
        u32x4 vf0 = *(const u32x4*)&Vt[t & 1][vrow * 64 + ((lg ^ (vrow & 7)) << 3)];
        u32x4 vf1 = *(const u32x4*)&Vt[t & 1][vrow * 64 + (((lg ^ 4) ^ (vrow & 7)) << 3)];
#pragma unroll
        for (int m = 0; m < 2; ++m) {
          xacc[m][db] = mfma16(pf[m][0], vf0, xacc[m][db]);
          xacc[m][db] = mfma16(pf[m][1], vf1, xacc[m][db]);
        }
      }
      __builtin_amdgcn_s_setprio(0);
    }
    // stage V(t+1) into the other buffer
#pragma unroll
    for (int i = 0; i < 2; ++i) {
      const int dk = vdk + i * 32;
      *(u32x4*)&Vt[(t + 1) & 1][dk * 64 + ((vc ^ (dk & 7)) << 3)] = vpre[i];
    }
  }

  // combine lg-group partials: lanes {lr, lr+16, lr+32, lr+48} hold row lr
#pragma unroll
  for (int m = 0; m < 2; ++m) {
    plsum[m] += __shfl_xor(plsum[m], 16);
    plsum[m] += __shfl_xor(plsum[m], 32);
  }

#pragma unroll
  for (int m = 0; m < 2; ++m)
#pragma unroll
    for (int r = 0; r < 4; ++r) {
      // row lg*4+r sum lives in lanes with lr == lg*4+r; width-16 shfl
      const float rs = __shfl(plsum[m], lg * 4 + r, 16);
      const float inv = 1.0f / fmaxf(rs, 1e-30f);
      const int srow = wrow + m * 16 + lg * 4 + r;
      const size_t base = ((size_t)b * S_LEN + srow) * D_DIM + h * DK;
#pragma unroll
      for (int db = 0; db < 4; ++db)
        Xb[base + db * 16 + lr] = f2bf(xacc[m][db][r] * inv);
    }
}

// ---- launcher ---------------------------------------------------------------
// d_out holds Qb+Kb (bf16, 33.55MB = out_size*4B). ws: VTb + Xb (+4x WT bf16).
extern "C" void kernel_launch(void* const* d_in, const int* in_sizes, int n_in,
                              void* d_out, int out_size, void* d_ws, size_t ws_size,
                              hipStream_t stream) {
  const float* q = (const float*)d_in[0];
  const float* k = (const float*)d_in[1];
  const float* v = (const float*)d_in[2];
  const float* Wq = (const float*)d_in[4];  const float* bq = (const float*)d_in[5];
  const float* Wk = (const float*)d_in[6];  const float* bk = (const float*)d_in[7];
  const float* Wv = (const float*)d_in[8];  const float* bv = (const float*)d_in[9];
  const float* Wo = (const float*)d_in[10]; const float* bo = (const float*)d_in[11];

  u16* Qb = (u16*)d_out;
  u16* Kb = Qb + (8u << 20);
  u16* VTb = (u16*)d_ws;
  u16* Xb = VTb + (8u << 20);

  const float scl = 0.125f * 1.4426950408889634f;  // 1/sqrt(DK) * log2(e)
  const dim3 tb(256);
  const size_t need = ((size_t)(8u << 20)) * 2 * 2 + 4 * ((size_t)(1u << 20)) * 2;

  if (ws_size >= need) {
    u16* WqT = Xb + (8u << 20);
    u16* WkT = WqT + (1u << 20);
    u16* WvT = WkT + (1u << 20);
    u16* WoT = WvT + (1u << 20);
    transpose_all<<<dim3(32, 32, 4), tb, 0, stream>>>(Wq, Wk, Wv, Wo, WqT, WkT, WvT, WoT);
    gemm_xw<1, 1><<<dim3(64, 8), tb, 0, stream>>>(q, WqT, bq, Qb, 1, scl);
    gemm_xw<1, 1><<<dim3(64, 8), tb, 0, stream>>>(k, WkT, bk, Kb, 1, 1.0f);
    gemm_xw<1, 1><<<dim3(64, 8), tb, 0, stream>>>(v, WvT, bv, VTb, 2, 1.0f);
    attn_kernel<<<dim3(1024), tb, 0, stream>>>(Qb, Kb, VTb, Xb);
    gemm_xw<0, 1><<<dim3(64, 8), tb, 0, stream>>>(Xb, WoT, bo, d_out, 0, 1.0f);
  } else {
    gemm_xw<1, 0><<<dim3(64, 8), tb, 0, stream>>>(q, Wq, bq, Qb, 1, scl);
    gemm_xw<1, 0><<<dim3(64, 8), tb, 0, stream>>>(k, Wk, bk, Kb, 1, 1.0f);
    gemm_xw<1, 0><<<dim3(64, 8), tb, 0, stream>>>(v, Wv, bv, VTb, 2, 1.0f);
    attn_kernel<<<dim3(1024), tb, 0, stream>>>(Qb, Kb, VTb, Xb);
    gemm_xw<0, 0><<<dim3(64, 8), tb, 0, stream>>>(Xb, Wo, bo, d_out, 0, 1.0f);
  }
}